// Round 6
// baseline (46.745 us; speedup 1.0000x reference)
//
#include <hip/hip_runtime.h>
#include <math.h>

#define DT 0.2f
#define LEN_HIST 16
#define MAX_PRED 32

// ws layout (floats): [0 .. 4B)  X per track (float4)
//                     [4B .. 4B+3*len_pred)  (sx, sy, rho) per step

// ---------------- shared covariance recursion (runs on one lane) ----------
__device__ __forceinline__ void riccati_lane0(
    const float* __restrict__ vsx_p, const float* __restrict__ vsy_p,
    const float* __restrict__ asx_p, const float* __restrict__ asy_p,
    const float* __restrict__ GR_p,  const float* __restrict__ coefG_p,
    float* sK, float* sC, int len_pred)
{
    const float Gv0 = DT * DT * 0.5f, Gv1 = DT, Gv2 = DT * DT * 0.5f, Gv3 = DT;
    float ax2 = asx_p[0] * asx_p[0];
    float ay2 = asy_p[0] * asy_p[0];
    float g[4];
    g[0] = Gv0 * tanhf(coefG_p[0]);
    g[1] = Gv1 * tanhf(coefG_p[1]);
    g[2] = Gv2 * tanhf(coefG_p[2]);
    g[3] = Gv3 * tanhf(coefG_p[3]);
    float Q[4][4];
    #pragma unroll
    for (int i = 0; i < 4; ++i)
        #pragma unroll
        for (int j = 0; j < 4; ++j) {
            float s = (i < 2) ? ((j < 2) ? ax2 : 1.0f)
                              : ((j < 2) ? 1.0f : ay2);
            Q[i][j] = g[i] * g[j] * s;
        }
    float GR0 = GR_p[0], GR1 = GR_p[1];
    float R00 = GR0 * GR0, R01 = GR0 * GR1, R10 = GR1 * GR0, R11 = GR1 * GR1;
    float P[4][4] = {};
    P[0][0] = R00; P[1][1] = vsx_p[0] * vsx_p[0];
    P[2][2] = R11; P[3][3] = vsy_p[0] * vsy_p[0];

    #pragma unroll
    for (int t = 1; t < LEN_HIST; ++t) {
        float T[4][4];
        #pragma unroll
        for (int j = 0; j < 4; ++j) {
            T[0][j] = P[0][j] + DT * P[1][j];
            T[1][j] = P[1][j];
            T[2][j] = P[2][j] + DT * P[3][j];
            T[3][j] = P[3][j];
        }
        #pragma unroll
        for (int i = 0; i < 4; ++i) {
            P[i][0] = T[i][0] + DT * T[i][1] + Q[i][0];
            P[i][1] = T[i][1]                + Q[i][1];
            P[i][2] = T[i][2] + DT * T[i][3] + Q[i][2];
            P[i][3] = T[i][3]                + Q[i][3];
        }
        float S00 = P[0][0] + R00, S01 = P[0][2] + R01;
        float S10 = P[2][0] + R10, S11 = P[2][2] + R11;
        float inv = 1.0f / (S00 * S11 - S01 * S10);
        float Si00 =  S11 * inv, Si01 = -S01 * inv;
        float Si10 = -S10 * inv, Si11 =  S00 * inv;
        float K[4][2];
        #pragma unroll
        for (int i = 0; i < 4; ++i) {
            K[i][0] = P[i][0] * Si00 + P[i][2] * Si10;
            K[i][1] = P[i][0] * Si01 + P[i][2] * Si11;
            sK[(t - 1) * 8 + i * 2 + 0] = K[i][0];
            sK[(t - 1) * 8 + i * 2 + 1] = K[i][1];
        }
        float U[4][4];
        #pragma unroll
        for (int i = 0; i < 4; ++i)
            #pragma unroll
            for (int j = 0; j < 4; ++j)
                U[i][j] = P[i][j] - K[i][0] * P[0][j] - K[i][1] * P[2][j];
        float w_[4];
        #pragma unroll
        for (int i = 0; i < 4; ++i)
            w_[i] = K[i][0] * GR0 + K[i][1] * GR1;
        #pragma unroll
        for (int i = 0; i < 4; ++i)
            #pragma unroll
            for (int j = 0; j < 4; ++j)
                P[i][j] = U[i][j] - U[i][0] * K[j][0] - U[i][2] * K[j][1] + w_[i] * w_[j];
    }
    for (int l = 0; l < len_pred; ++l) {
        float T[4][4];
        #pragma unroll
        for (int j = 0; j < 4; ++j) {
            T[0][j] = P[0][j] + DT * P[1][j];
            T[1][j] = P[1][j];
            T[2][j] = P[2][j] + DT * P[3][j];
            T[3][j] = P[3][j];
        }
        #pragma unroll
        for (int i = 0; i < 4; ++i) {
            P[i][0] = T[i][0] + DT * T[i][1] + Q[i][0];
            P[i][1] = T[i][1]                + Q[i][1];
            P[i][2] = T[i][2] + DT * T[i][3] + Q[i][2];
            P[i][3] = T[i][3]                + Q[i][3];
        }
        float sx = sqrtf(P[0][0]);
        float sy = sqrtf(P[2][2]);
        sC[l * 3 + 0] = sx;
        sC[l * 3 + 1] = sy;
        sC[l * 3 + 2] = (P[0][2] + P[2][0]) / (2.0f * sx * sy);
    }
}

// ---------------- kernel 1: per-track filter -> X (float4) in ws ----------
__global__ __launch_bounds__(256) void k1_filter(
    const float* __restrict__ hist,
    const float* __restrict__ vsx, const float* __restrict__ vsy,
    const float* __restrict__ asx, const float* __restrict__ asy,
    const float* __restrict__ GR,  const float* __restrict__ coefG,
    float* __restrict__ ws, int B, int len_pred)
{
    __shared__ float sK[15 * 8];
    __shared__ float sCl[3 * MAX_PRED];

    const int tid = threadIdx.x;
    const int b = blockIdx.x * 256 + tid;
    const int ib = (b < B) ? b : (B - 1);

    // issue measurement loads first; latency hides under the serial Riccati
    float2 z[LEN_HIST];
    #pragma unroll
    for (int t = 0; t < LEN_HIST; ++t)
        z[t] = *reinterpret_cast<const float2*>(hist + ((size_t)t * B + ib) * 2);

    if (tid == 0)
        riccati_lane0(vsx, vsy, asx, asy, GR, coefG, sK, sCl, len_pred);
    __syncthreads();

    if (blockIdx.x == 0)
        for (int i = tid; i < 3 * len_pred; i += 256)
            ws[4 * (size_t)B + i] = sCl[i];

    if (b >= B) return;

    float X0 = z[0].x, X1 = (z[1].x - z[0].x) / DT;
    float X2 = z[0].y, X3 = (z[1].y - z[0].y) / DT;

    #pragma unroll
    for (int t = 1; t < LEN_HIST; ++t) {
        const float4 kx = *reinterpret_cast<const float4*>(&sK[(t - 1) * 8]);
        const float4 ky = *reinterpret_cast<const float4*>(&sK[(t - 1) * 8 + 4]);
        X0 += DT * X1; X2 += DT * X3;
        float y0 = z[t].x - X0, y1 = z[t].y - X2;
        X0 += kx.x * y0 + kx.y * y1;
        X1 += kx.z * y0 + kx.w * y1;
        X2 += ky.x * y0 + ky.y * y1;
        X3 += ky.z * y0 + ky.w * y1;
    }

    reinterpret_cast<float4*>(ws)[b] = make_float4(X0, X1, X2, X3);
}

// ---------------- kernel 2: streaming output emission ---------------------
// one float4 of out per thread; grid = (ceil(perL4/256), len_pred)
__global__ __launch_bounds__(256) void k2_emit(
    const float* __restrict__ ws, float* __restrict__ out, int B, int perL4)
{
    const int l = blockIdx.y;
    const int k = blockIdx.x * 256 + threadIdx.x;
    if (k >= perL4) return;

    const float4* __restrict__ Xb = reinterpret_cast<const float4*>(ws);
    const float* __restrict__ sC = ws + 4 * (size_t)B;
    const float sx = sC[3 * l], sy = sC[3 * l + 1], rho = sC[3 * l + 2];
    const float t = (float)(l + 1) * DT;

    const int f = 4 * k;           // float index within this layer
    const int b0 = f / 5;          // constant divisor -> magic mul
    const int c0 = f - b0 * 5;

    const float4 Xa = Xb[b0];
    const float4 Xn = Xb[b0 + 1];  // in-bounds of ws (sC slack) even at b0==B-1

    const float muxA = fmaf(t, Xa.y, Xa.x);
    const float muyA = fmaf(t, Xa.w, Xa.z);
    const float muxN = fmaf(t, Xn.y, Xn.x);
    const float muyN = fmaf(t, Xn.w, Xn.z);

    float v[4];
    #pragma unroll
    for (int j = 0; j < 4; ++j) {
        const int cc = c0 + j;     // 0..7  (cc-5 indexes next track's columns)
        v[j] = (cc == 0) ? muxA :
               (cc == 1) ? muyA :
               (cc == 2) ? sx :
               (cc == 3) ? sy :
               (cc == 4) ? rho :
               (cc == 5) ? muxN :
               (cc == 6) ? muyN : sx;   // cc==7 -> next track col 2 = sx (shared)
    }
    reinterpret_cast<float4*>(out)[(size_t)l * perL4 + k] =
        make_float4(v[0], v[1], v[2], v[3]);
}

// ---------------- fallback: proven monolithic kernel (round 1) ------------
__global__ __launch_bounds__(256) void kalman_mono(
    const float* __restrict__ hist,
    const float* __restrict__ vsx_p, const float* __restrict__ vsy_p,
    const float* __restrict__ asx_p, const float* __restrict__ asy_p,
    const float* __restrict__ GR_p,  const float* __restrict__ coefG_p,
    float* __restrict__ out, int B, int len_pred)
{
    int b = blockIdx.x * blockDim.x + threadIdx.x;
    if (b >= B) return;

    const float Gv0 = DT * DT * 0.5f, Gv1 = DT, Gv2 = DT * DT * 0.5f, Gv3 = DT;
    float ax2 = asx_p[0] * asx_p[0];
    float ay2 = asy_p[0] * asy_p[0];
    float g[4];
    g[0] = Gv0 * tanhf(coefG_p[0]);
    g[1] = Gv1 * tanhf(coefG_p[1]);
    g[2] = Gv2 * tanhf(coefG_p[2]);
    g[3] = Gv3 * tanhf(coefG_p[3]);
    float Q[4][4];
    #pragma unroll
    for (int i = 0; i < 4; ++i)
        #pragma unroll
        for (int j = 0; j < 4; ++j) {
            float s = (i < 2) ? ((j < 2) ? ax2 : 1.0f)
                              : ((j < 2) ? 1.0f : ay2);
            Q[i][j] = g[i] * g[j] * s;
        }
    float GR0 = GR_p[0], GR1 = GR_p[1];
    float R00 = GR0 * GR0, R01 = GR0 * GR1, R10 = GR1 * GR0, R11 = GR1 * GR1;

    float2 z[LEN_HIST];
    #pragma unroll
    for (int t = 0; t < LEN_HIST; ++t)
        z[t] = *reinterpret_cast<const float2*>(hist + ((size_t)t * B + b) * 2);

    float X0 = z[0].x, X1 = (z[1].x - z[0].x) / DT;
    float X2 = z[0].y, X3 = (z[1].y - z[0].y) / DT;
    float P[4][4] = {};
    P[0][0] = R00; P[1][1] = vsx_p[0] * vsx_p[0];
    P[2][2] = R11; P[3][3] = vsy_p[0] * vsy_p[0];

    #pragma unroll
    for (int t = 1; t < LEN_HIST; ++t) {
        float T[4][4];
        #pragma unroll
        for (int j = 0; j < 4; ++j) {
            T[0][j] = P[0][j] + DT * P[1][j];
            T[1][j] = P[1][j];
            T[2][j] = P[2][j] + DT * P[3][j];
            T[3][j] = P[3][j];
        }
        #pragma unroll
        for (int i = 0; i < 4; ++i) {
            P[i][0] = T[i][0] + DT * T[i][1] + Q[i][0];
            P[i][1] = T[i][1]                + Q[i][1];
            P[i][2] = T[i][2] + DT * T[i][3] + Q[i][2];
            P[i][3] = T[i][3]                + Q[i][3];
        }
        float y0 = z[t].x - X0 - DT * X1;
        float y1 = z[t].y - X2 - DT * X3;
        X0 += DT * X1; X2 += DT * X3;
        float S00 = P[0][0] + R00, S01 = P[0][2] + R01;
        float S10 = P[2][0] + R10, S11 = P[2][2] + R11;
        float inv = 1.0f / (S00 * S11 - S01 * S10);
        float Si00 =  S11 * inv, Si01 = -S01 * inv;
        float Si10 = -S10 * inv, Si11 =  S00 * inv;
        float K[4][2];
        #pragma unroll
        for (int i = 0; i < 4; ++i) {
            K[i][0] = P[i][0] * Si00 + P[i][2] * Si10;
            K[i][1] = P[i][0] * Si01 + P[i][2] * Si11;
        }
        X0 += K[0][0] * y0 + K[0][1] * y1;
        X1 += K[1][0] * y0 + K[1][1] * y1;
        X2 += K[2][0] * y0 + K[2][1] * y1;
        X3 += K[3][0] * y0 + K[3][1] * y1;
        float U[4][4];
        #pragma unroll
        for (int i = 0; i < 4; ++i)
            #pragma unroll
            for (int j = 0; j < 4; ++j)
                U[i][j] = P[i][j] - K[i][0] * P[0][j] - K[i][1] * P[2][j];
        float w_[4];
        #pragma unroll
        for (int i = 0; i < 4; ++i)
            w_[i] = K[i][0] * GR0 + K[i][1] * GR1;
        #pragma unroll
        for (int i = 0; i < 4; ++i)
            #pragma unroll
            for (int j = 0; j < 4; ++j)
                P[i][j] = U[i][j] - U[i][0] * K[j][0] - U[i][2] * K[j][1] + w_[i] * w_[j];
    }

    size_t ob = (size_t)b * 5;
    for (int l = 0; l < len_pred; ++l) {
        X0 += DT * X1; X2 += DT * X3;
        float T[4][4];
        #pragma unroll
        for (int j = 0; j < 4; ++j) {
            T[0][j] = P[0][j] + DT * P[1][j];
            T[1][j] = P[1][j];
            T[2][j] = P[2][j] + DT * P[3][j];
            T[3][j] = P[3][j];
        }
        #pragma unroll
        for (int i = 0; i < 4; ++i) {
            P[i][0] = T[i][0] + DT * T[i][1] + Q[i][0];
            P[i][1] = T[i][1]                + Q[i][1];
            P[i][2] = T[i][2] + DT * T[i][3] + Q[i][2];
            P[i][3] = T[i][3]                + Q[i][3];
        }
        float sx = sqrtf(P[0][0]);
        float sy = sqrtf(P[2][2]);
        float rho = (P[0][2] + P[2][0]) / (2.0f * sx * sy);
        float* o = out + (size_t)l * B * 5 + ob;
        o[0] = X0; o[1] = X2; o[2] = sx; o[3] = sy; o[4] = rho;
    }
}

extern "C" void kernel_launch(void* const* d_in, const int* in_sizes, int n_in,
                              void* d_out, int out_size, void* d_ws, size_t ws_size,
                              hipStream_t stream) {
    const float* hist  = (const float*)d_in[0];
    const float* vsx   = (const float*)d_in[1];
    const float* vsy   = (const float*)d_in[2];
    const float* asx   = (const float*)d_in[3];
    const float* asy   = (const float*)d_in[4];
    const float* GR    = (const float*)d_in[5];
    const float* coefG = (const float*)d_in[6];
    float* out = (float*)d_out;
    float* ws  = (float*)d_ws;

    int B = in_sizes[0] / (LEN_HIST * 2);
    int len_pred = out_size / (B * 5);
    if (len_pred > MAX_PRED) len_pred = MAX_PRED;

    size_t ws_need = (4 * (size_t)B + 3 * (size_t)len_pred) * sizeof(float)
                     + sizeof(float4); // slack for the unconditional Xb[b0+1] load
    bool fast = (((size_t)B * 5) % 4 == 0) && ws_size >= ws_need;

    if (fast) {
        int perL4 = (B * 5) / 4;
        k1_filter<<<(B + 255) / 256, 256, 0, stream>>>(hist, vsx, vsy, asx, asy,
                                                       GR, coefG, ws, B, len_pred);
        dim3 g2((perL4 + 255) / 256, len_pred);
        k2_emit<<<g2, 256, 0, stream>>>(ws, out, B, perL4);
    } else {
        kalman_mono<<<(B + 255) / 256, 256, 0, stream>>>(hist, vsx, vsy, asx, asy,
                                                         GR, coefG, out, B, len_pred);
    }
}

// Round 7
// 34.104 us; speedup vs baseline: 1.3707x; 1.3707x over previous
//
#include <hip/hip_runtime.h>
#include <math.h>

#define DT 0.2f
#define LEN_HIST 16
#define MAX_PRED 32
#define TPB 256   // threads per block == tracks per block (1 track/thread)

__global__ __launch_bounds__(TPB) void kalman_v2(
    const float* __restrict__ hist,
    const float* __restrict__ vsx_p, const float* __restrict__ vsy_p,
    const float* __restrict__ asx_p, const float* __restrict__ asy_p,
    const float* __restrict__ GR_p,  const float* __restrict__ coefG_p,
    float* __restrict__ out, int B, int len_pred)
{
    __shared__ __align__(16) float sK[15 * 8];        // Kalman gains
    __shared__ float sC[3 * MAX_PRED];                // (sx, sy, rho) per step
    __shared__ __align__(16) float sT[TPB / 64][2][320]; // per-wave transpose bufs

    const int tid  = threadIdx.x;
    const int base = blockIdx.x * TPB;
    const int b    = base + tid;
    const bool vOK = b < B;
    const int ib   = vOK ? b : (B - 1);

    // ---- issue all measurement loads first (latency hides under Riccati) ----
    float2 z[LEN_HIST];
    #pragma unroll
    for (int t = 0; t < LEN_HIST; ++t)
        z[t] = *reinterpret_cast<const float2*>(hist + ((size_t)t * B + ib) * 2);

    // ---- shared covariance recursion: once per block on lane 0 ----
    if (tid == 0) {
        const float Gv0 = DT * DT * 0.5f, Gv1 = DT, Gv2 = DT * DT * 0.5f, Gv3 = DT;
        float ax2 = asx_p[0] * asx_p[0];
        float ay2 = asy_p[0] * asy_p[0];
        float g[4];
        g[0] = Gv0 * tanhf(coefG_p[0]);
        g[1] = Gv1 * tanhf(coefG_p[1]);
        g[2] = Gv2 * tanhf(coefG_p[2]);
        g[3] = Gv3 * tanhf(coefG_p[3]);
        float Q[4][4];
        #pragma unroll
        for (int i = 0; i < 4; ++i)
            #pragma unroll
            for (int j = 0; j < 4; ++j) {
                float s = (i < 2) ? ((j < 2) ? ax2 : 1.0f)
                                  : ((j < 2) ? 1.0f : ay2);
                Q[i][j] = g[i] * g[j] * s;
            }
        float GR0 = GR_p[0], GR1 = GR_p[1];
        float R00 = GR0 * GR0, R01 = GR0 * GR1, R10 = GR1 * GR0, R11 = GR1 * GR1;
        float P[4][4] = {};
        P[0][0] = R00; P[1][1] = vsx_p[0] * vsx_p[0];
        P[2][2] = R11; P[3][3] = vsy_p[0] * vsy_p[0];

        #pragma unroll
        for (int t = 1; t < LEN_HIST; ++t) {
            float T[4][4];
            #pragma unroll
            for (int j = 0; j < 4; ++j) {
                T[0][j] = P[0][j] + DT * P[1][j];
                T[1][j] = P[1][j];
                T[2][j] = P[2][j] + DT * P[3][j];
                T[3][j] = P[3][j];
            }
            #pragma unroll
            for (int i = 0; i < 4; ++i) {
                P[i][0] = T[i][0] + DT * T[i][1] + Q[i][0];
                P[i][1] = T[i][1]                + Q[i][1];
                P[i][2] = T[i][2] + DT * T[i][3] + Q[i][2];
                P[i][3] = T[i][3]                + Q[i][3];
            }
            float S00 = P[0][0] + R00, S01 = P[0][2] + R01;
            float S10 = P[2][0] + R10, S11 = P[2][2] + R11;
            float inv = 1.0f / (S00 * S11 - S01 * S10);
            float Si00 =  S11 * inv, Si01 = -S01 * inv;
            float Si10 = -S10 * inv, Si11 =  S00 * inv;
            float K[4][2];
            #pragma unroll
            for (int i = 0; i < 4; ++i) {
                K[i][0] = P[i][0] * Si00 + P[i][2] * Si10;
                K[i][1] = P[i][0] * Si01 + P[i][2] * Si11;
                sK[(t - 1) * 8 + i * 2 + 0] = K[i][0];
                sK[(t - 1) * 8 + i * 2 + 1] = K[i][1];
            }
            float U[4][4];
            #pragma unroll
            for (int i = 0; i < 4; ++i)
                #pragma unroll
                for (int j = 0; j < 4; ++j)
                    U[i][j] = P[i][j] - K[i][0] * P[0][j] - K[i][1] * P[2][j];
            float w_[4];
            #pragma unroll
            for (int i = 0; i < 4; ++i)
                w_[i] = K[i][0] * GR0 + K[i][1] * GR1;
            #pragma unroll
            for (int i = 0; i < 4; ++i)
                #pragma unroll
                for (int j = 0; j < 4; ++j)
                    P[i][j] = U[i][j] - U[i][0] * K[j][0] - U[i][2] * K[j][1] + w_[i] * w_[j];
        }
        for (int l = 0; l < len_pred; ++l) {
            float T[4][4];
            #pragma unroll
            for (int j = 0; j < 4; ++j) {
                T[0][j] = P[0][j] + DT * P[1][j];
                T[1][j] = P[1][j];
                T[2][j] = P[2][j] + DT * P[3][j];
                T[3][j] = P[3][j];
            }
            #pragma unroll
            for (int i = 0; i < 4; ++i) {
                P[i][0] = T[i][0] + DT * T[i][1] + Q[i][0];
                P[i][1] = T[i][1]                + Q[i][1];
                P[i][2] = T[i][2] + DT * T[i][3] + Q[i][2];
                P[i][3] = T[i][3]                + Q[i][3];
            }
            float sx = sqrtf(P[0][0]);
            float sy = sqrtf(P[2][2]);
            sC[l * 3 + 0] = sx;
            sC[l * 3 + 1] = sy;
            sC[l * 3 + 2] = (P[0][2] + P[2][0]) / (2.0f * sx * sy);
        }
    }
    __syncthreads();

    // ---- per-track state filter (12 fma/step) ----
    float X0 = z[0].x, X1 = (z[1].x - z[0].x) / DT;
    float X2 = z[0].y, X3 = (z[1].y - z[0].y) / DT;

    #pragma unroll
    for (int t = 1; t < LEN_HIST; ++t) {
        const float4 kx = *reinterpret_cast<const float4*>(&sK[(t - 1) * 8]);
        const float4 ky = *reinterpret_cast<const float4*>(&sK[(t - 1) * 8 + 4]);
        X0 += DT * X1; X2 += DT * X3;
        float y0 = z[t].x - X0, y1 = z[t].y - X2;
        X0 += kx.x * y0 + kx.y * y1;
        X1 += kx.z * y0 + kx.w * y1;
        X2 += ky.x * y0 + ky.y * y1;
        X3 += ky.z * y0 + ky.w * y1;
    }

    // ---- predict + coalesced store via per-wave LDS transpose ----
    const int lane = tid & 63, w = tid >> 6;
    const int g = base + w * 64;                 // first track of this wave
    const bool fullWave = (g + 63) < B;
    const bool alignOK = (((size_t)B * 5) & 3) == 0;

    for (int l = 0; l < len_pred; ++l) {
        X0 += DT * X1; X2 += DT * X3;
        const float cx = sC[3 * l], cy = sC[3 * l + 1], cr = sC[3 * l + 2];

        if (fullWave && alignOK) {
            float* buf = &sT[w][l & 1][0];
            __builtin_amdgcn_wave_barrier();
            buf[lane * 5 + 0] = X0;
            buf[lane * 5 + 1] = X2;
            buf[lane * 5 + 2] = cx;
            buf[lane * 5 + 3] = cy;
            buf[lane * 5 + 4] = cr;
            __builtin_amdgcn_wave_barrier();
            float* o = out + ((size_t)l * B + g) * 5;
            *reinterpret_cast<float4*>(o + lane * 4) =
                *reinterpret_cast<const float4*>(&buf[lane * 4]);
            o[256 + lane] = buf[256 + lane];
        } else if (vOK) {
            float* o = out + ((size_t)l * B + b) * 5;
            o[0] = X0; o[1] = X2; o[2] = cx; o[3] = cy; o[4] = cr;
        }
    }
}

extern "C" void kernel_launch(void* const* d_in, const int* in_sizes, int n_in,
                              void* d_out, int out_size, void* d_ws, size_t ws_size,
                              hipStream_t stream) {
    const float* hist  = (const float*)d_in[0];
    const float* vsx   = (const float*)d_in[1];
    const float* vsy   = (const float*)d_in[2];
    const float* asx   = (const float*)d_in[3];
    const float* asy   = (const float*)d_in[4];
    const float* GR    = (const float*)d_in[5];
    const float* coefG = (const float*)d_in[6];
    float* out = (float*)d_out;

    int B = in_sizes[0] / (LEN_HIST * 2);
    int len_pred = out_size / (B * 5);
    if (len_pred > MAX_PRED) len_pred = MAX_PRED;

    int grid = (B + TPB - 1) / TPB;
    kalman_v2<<<grid, TPB, 0, stream>>>(hist, vsx, vsy, asx, asy, GR, coefG,
                                        out, B, len_pred);
}